// Round 4
// baseline (173.919 us; speedup 1.0000x reference)
//
#include <hip/hip_runtime.h>

// GRUCell (B=262144, IN=2, H=50) + critic + actor-softmax.
// Inputs fp32, OUTPUTS fp32 (reference returns float32; harness contract:
// "else float*"). d_out = h_new[B,50] | c[B,1] | pi[B,2], flat fp32.
// Extended-K MFMA: x[64]=[h(50),s(2),1,0...], W[64]=[w_hh,w_ih,bias,0...]
// -> one bf16 16x16x32 MFMA pass gives full r/z pre-activations; n-gate
// keeps i_n separate (r multiplies only h_n). All recombination in fp32.
// D-layout probed at runtime (A=I through the same staging conventions),
// so (lane,reg)->(row,col) placement is correct by construction.

#define BDIM 256

typedef __bf16 bf16x8 __attribute__((ext_vector_type(8)));
typedef float f32x4 __attribute__((ext_vector_type(4)));

__device__ __forceinline__ unsigned short f2bf(float f) {
    union { float f; unsigned u; } x; x.f = f;
    unsigned r = x.u + 0x7fffu + ((x.u >> 16) & 1u);
    return (unsigned short)(r >> 16);
}

__global__ __launch_bounds__(BDIM) void gru_fused(
    const float* __restrict__ s,
    const float* __restrict__ h,
    const float* __restrict__ w_ih,
    const float* __restrict__ w_hh,
    const float* __restrict__ b_ih,
    const float* __restrict__ b_hh,
    const float* __restrict__ actor_w,
    const float* __restrict__ actor_b,
    const float* __restrict__ critic_w,
    const float* __restrict__ critic_b,
    float* __restrict__ out,
    int Btot, int nTiles)
{
    // bf16 x-tile: 64 rows x 72 (stride 144B: 16B-aligned)
    __shared__ __align__(16) unsigned short xlds[64 * 72];
    // weight B-fragments: [g(3)][t(4)][ks(2)][lane(64)][8 bf16]
    __shared__ __align__(16) unsigned short wlds[1536 * 8];
    __shared__ float hlds[64 * 53];   // fp32 h, overwritten with fp32 h_new
    __shared__ float sflds[64 * 2];   // fp32 s
    __shared__ float awc[150];        // actor_w row0, row1, critic_w (fp32)
    __shared__ float win0l[64], win1l[64], binl[64];  // n-gate in-weights by col

    const int tid  = threadIdx.x;
    const int wave = tid >> 6;
    const int lane = tid & 63;
    const int c16  = lane & 15;
    const int quad = lane >> 4;

    // ---- one-time: swizzled bf16 weight fragments into LDS ----
    for (int e = tid; e < 1536; e += BDIM) {
        int ln = e & 63;
        int ks = (e >> 6) & 1;
        int t  = (e >> 7) & 3;
        int g  = e >> 9;
        int n  = t * 16 + (ln & 15);
        int kbase = ks * 32 + (ln >> 4) * 8;
        unsigned short vals[8];
        if (n < 50) {
            int r = g * 50 + n;
            #pragma unroll
            for (int i = 0; i < 8; ++i) {
                int k = kbase + i;
                float v = 0.f;
                if (k < 50)       v = w_hh[r * 50 + k];
                else if (k == 50) v = (g < 2) ? w_ih[r * 2 + 0] : 0.f;
                else if (k == 51) v = (g < 2) ? w_ih[r * 2 + 1] : 0.f;
                else if (k == 52) {
                    v = b_hh[r];                 // n-gate: b_hh only
                    if (g < 2) v += b_ih[r];     // r/z: both biases fused
                }
                vals[i] = f2bf(v);
            }
        } else {
            #pragma unroll
            for (int i = 0; i < 8; ++i) vals[i] = 0;
        }
        #pragma unroll
        for (int i = 0; i < 8; ++i) wlds[e * 8 + i] = vals[i];
    }
    // head weights -> LDS (fp32)
    for (int k = tid; k < 50; k += BDIM) {
        awc[k]       = actor_w[k];
        awc[50 + k]  = actor_w[50 + k];
        awc[100 + k] = critic_w[k];
    }
    // n-gate input weights -> LDS, indexed by output column (zero-padded)
    if (tid < 64) {
        int j = tid;
        float w0 = 0.f, w1 = 0.f, bb = 0.f;
        if (j < 50) {
            w0 = w_ih[(100 + j) * 2 + 0];
            w1 = w_ih[(100 + j) * 2 + 1];
            bb = b_ih[100 + j];
        }
        win0l[j] = w0; win1l[j] = w1; binl[j] = bb;
    }

    // ---- runtime D-placement probe (same staging conventions as main MFMA) ----
    union U { unsigned short u[8]; bf16x8 v; };
    U aI, bN, bK;
    #pragma unroll
    for (int i = 0; i < 8; ++i) {
        int k = quad * 8 + i;
        aI.u[i] = (k == c16) ? (unsigned short)0x3F80 : (unsigned short)0;
        bN.u[i] = (k < 16) ? f2bf((float)c16) : (unsigned short)0;
        bK.u[i] = (k < 16) ? f2bf((float)k)   : (unsigned short)0;
    }
    f32x4 d1 = {0.f, 0.f, 0.f, 0.f}, d2 = {0.f, 0.f, 0.f, 0.f};
    d1 = __builtin_amdgcn_mfma_f32_16x16x32_bf16(aI.v, bN.v, d1, 0, 0, 0);
    d2 = __builtin_amdgcn_mfma_f32_16x16x32_bf16(aI.v, bK.v, d2, 0, 0, 0);
    int colmap[4], rowmap[4];
    #pragma unroll
    for (int r = 0; r < 4; ++r) {
        colmap[r] = ((int)(d1[r] + 0.5f)) & 15;
        rowmap[r] = ((int)(d2[r] + 0.5f)) & 15;
    }

    const float2* h2 = (const float2*)h;
    const float2* s2 = (const float2*)s;
    unsigned* xlds32 = (unsigned*)xlds;
    float2* out2 = (float2*)out;
    const long long outc_off   = (long long)Btot * 50;         // c, float idx
    const long long outpi2_off = ((long long)Btot * 51) >> 1;  // pi, float2 idx

    __syncthreads();

    for (int bt = blockIdx.x; bt < nTiles; bt += gridDim.x) {
        const int rowbase = bt * 64;

        // ---- stage x tile: h via float2 (coalesced), bf16 + fp32 copies ----
        for (int d = tid; d < 1600; d += BDIM) {
            int r = d / 25, dk = d - r * 25;
            float2 v = h2[rowbase * 25 + d];
            xlds32[r * 36 + dk] = (unsigned)f2bf(v.x) | ((unsigned)f2bf(v.y) << 16);
            hlds[r * 53 + 2 * dk]     = v.x;
            hlds[r * 53 + 2 * dk + 1] = v.y;
        }
        if (tid < 64) {
            float2 sv = s2[rowbase + tid];
            sflds[tid * 2 + 0] = sv.x;
            sflds[tid * 2 + 1] = sv.y;
            xlds32[tid * 36 + 25] = (unsigned)f2bf(sv.x) | ((unsigned)f2bf(sv.y) << 16);
            xlds32[tid * 36 + 26] = 0x00003f80u;          // k=52: 1.0 bf16, k=53: 0
            #pragma unroll
            for (int q = 27; q < 32; ++q) xlds32[tid * 36 + q] = 0u;  // k=54..63
        }
        __syncthreads();

        // ---- MFMA: pre-activations for 16 rows x (3 gates x 64 cols) per wave ----
        const unsigned short* arow = &xlds[(wave * 16 + c16) * 72 + quad * 8];
        bf16x8 a0 = *(const bf16x8*)(arow);        // k 0..31
        bf16x8 a1 = *(const bf16x8*)(arow + 32);   // k 32..63
        f32x4 acc[3][4];
        #pragma unroll
        for (int g = 0; g < 3; ++g) {
            #pragma unroll
            for (int t = 0; t < 4; ++t) {
                f32x4 a = {0.f, 0.f, 0.f, 0.f};
                const unsigned short* wb = &wlds[(((g * 4 + t) * 2) * 64 + lane) * 8];
                bf16x8 b0 = *(const bf16x8*)(wb);
                bf16x8 b1 = *(const bf16x8*)(wb + 64 * 8);
                a = __builtin_amdgcn_mfma_f32_16x16x32_bf16(a0, b0, a, 0, 0, 0);
                a = __builtin_amdgcn_mfma_f32_16x16x32_bf16(a1, b1, a, 0, 0, 0);
                acc[g][t] = a;
            }
        }

        // ---- gate math (fp32) using probed D placement; h_new -> hlds ----
        #pragma unroll
        for (int reg = 0; reg < 4; ++reg) {
            int lr = wave * 16 + rowmap[reg];
            float s0 = sflds[lr * 2 + 0];
            float s1 = sflds[lr * 2 + 1];
            int cl = colmap[reg];
            #pragma unroll
            for (int t = 0; t < 4; ++t) {
                int j = t * 16 + cl;
                float pr = acc[0][t][reg];
                float pz = acc[1][t][reg];
                float hn = acc[2][t][reg];
                float inn = fmaf(s1, win1l[j], fmaf(s0, win0l[j], binl[j]));
                float rg = __builtin_amdgcn_rcpf(1.f + __expf(-pr));
                float zg = __builtin_amdgcn_rcpf(1.f + __expf(-pz));
                float x = inn + rg * hn;
                x = fminf(fmaxf(x, -20.f), 20.f);
                float e2 = __expf(2.f * x);
                float ng = (e2 - 1.f) * __builtin_amdgcn_rcpf(e2 + 1.f);
                if (j < 50) {
                    float hv = hlds[lr * 53 + j];
                    hlds[lr * 53 + j] = (1.f - zg) * ng + zg * hv;
                }
            }
        }
        __syncthreads();

        // ---- phase 2: coalesced fp32 h_new store + heads ----
        for (int d = tid; d < 1600; d += BDIM) {
            int r = d / 25, dk = d - r * 25;
            float2 v;
            v.x = hlds[r * 53 + 2 * dk];
            v.y = hlds[r * 53 + 2 * dk + 1];
            out2[rowbase * 25 + d] = v;
        }
        if (tid < 64) {
            int gr = rowbase + tid;
            float a0f = actor_b[0], a1f = actor_b[1], cc = critic_b[0];
            #pragma unroll 10
            for (int k = 0; k < 50; ++k) {
                float hv = hlds[tid * 53 + k];
                a0f = fmaf(hv, awc[k], a0f);
                a1f = fmaf(hv, awc[50 + k], a1f);
                cc  = fmaf(hv, awc[100 + k], cc);
            }
            out[outc_off + gr] = cc;
            float m = fmaxf(a0f, a1f);
            float e0 = __expf(a0f - m), e1 = __expf(a1f - m);
            float inv = 1.f / (e0 + e1);
            float2 pv; pv.x = e0 * inv; pv.y = e1 * inv;
            out2[outpi2_off + gr] = pv;
        }
        __syncthreads();
    }
}

extern "C" void kernel_launch(void* const* d_in, const int* in_sizes, int n_in,
                              void* d_out, int out_size, void* d_ws, size_t ws_size,
                              hipStream_t stream) {
    const float* s        = (const float*)d_in[0];
    const float* h        = (const float*)d_in[1];
    const float* w_ih     = (const float*)d_in[2];
    const float* w_hh     = (const float*)d_in[3];
    const float* b_ih     = (const float*)d_in[4];
    const float* b_hh     = (const float*)d_in[5];
    const float* actor_w  = (const float*)d_in[6];
    const float* actor_b  = (const float*)d_in[7];
    const float* critic_w = (const float*)d_in[8];
    const float* critic_b = (const float*)d_in[9];
    float* out = (float*)d_out;

    int Btot = in_sizes[1] / 50;          // 262144
    int nTiles = Btot / 64;               // 4096 (exact)
    int grid = nTiles < 1024 ? nTiles : 1024;

    gru_fused<<<grid, BDIM, 0, stream>>>(s, h, w_ih, w_hh, b_ih, b_hh,
                                         actor_w, actor_b, critic_w, critic_b,
                                         out, Btot, nTiles);
}

// Round 5
// 143.385 us; speedup vs baseline: 1.2129x; 1.2129x over previous
//
#include <hip/hip_runtime.h>

// GRUCell (B=262144, IN=2, H=50) + critic + actor-softmax.
// Inputs fp32, outputs fp32: d_out = h_new[B,50] | c[B,1] | pi[B,2].
// Extended-K MFMA: x[64]=[h(50),s(2),1,0...], W[64]=[w_hh,w_ih,bias,0...].
// R5: register-prefetch double buffering (HBM latency overlapped with
// compute), hlds dropped (bf16 recombination; h_new fp32 straight to
// global) -> LDS ~35.7KB -> 4 blocks/CU, heads parallelized across all
// 256 threads (4 lanes/row split-K + shfl_xor reduce).

#define BDIM 256

typedef __bf16 bf16x8 __attribute__((ext_vector_type(8)));
typedef float f32x4 __attribute__((ext_vector_type(4)));

__device__ __forceinline__ float bf2f(unsigned short u) {
    union { unsigned u; float f; } x; x.u = ((unsigned)u) << 16; return x.f;
}
__device__ __forceinline__ unsigned short f2bf(float f) {
    union { float f; unsigned u; } x; x.f = f;
    unsigned r = x.u + 0x7fffu + ((x.u >> 16) & 1u);
    return (unsigned short)(r >> 16);
}
__device__ __forceinline__ unsigned packbf(float a, float b) {
    return (unsigned)f2bf(a) | ((unsigned)f2bf(b) << 16);
}

__global__ __launch_bounds__(BDIM, 4) void gru_fused(
    const float* __restrict__ s,
    const float* __restrict__ h,
    const float* __restrict__ w_ih,
    const float* __restrict__ w_hh,
    const float* __restrict__ b_ih,
    const float* __restrict__ b_hh,
    const float* __restrict__ actor_w,
    const float* __restrict__ actor_b,
    const float* __restrict__ critic_w,
    const float* __restrict__ critic_b,
    float* __restrict__ out,
    int Btot, int nTiles)
{
    // bf16 x-tile: 64 rows x 72 (144B stride, 16B-aligned); holds h then h_new
    __shared__ __align__(16) unsigned short xlds[64 * 72];
    // weight B-fragments: [g(3)][t(4)][ks(2)][lane(64)][8 bf16]
    __shared__ __align__(16) unsigned short wlds[1536 * 8];
    __shared__ float sflds[64 * 2];                   // fp32 s
    __shared__ float awc[152];                        // actor r0|r1|critic|pad0
    __shared__ float win0l[64], win1l[64], binl[64];  // n-gate in-weights by col

    const int tid  = threadIdx.x;
    const int wave = tid >> 6;
    const int lane = tid & 63;
    const int c16  = lane & 15;
    const int quad = lane >> 4;

    // ---- one-time: swizzled bf16 weight fragments into LDS ----
    for (int e = tid; e < 1536; e += BDIM) {
        int ln = e & 63;
        int ks = (e >> 6) & 1;
        int t  = (e >> 7) & 3;
        int g  = e >> 9;
        int n  = t * 16 + (ln & 15);
        int kbase = ks * 32 + (ln >> 4) * 8;
        unsigned short vals[8];
        if (n < 50) {
            int r = g * 50 + n;
            #pragma unroll
            for (int i = 0; i < 8; ++i) {
                int k = kbase + i;
                float v = 0.f;
                if (k < 50)       v = w_hh[r * 50 + k];
                else if (k == 50) v = (g < 2) ? w_ih[r * 2 + 0] : 0.f;
                else if (k == 51) v = (g < 2) ? w_ih[r * 2 + 1] : 0.f;
                else if (k == 52) {
                    v = b_hh[r];                 // n-gate: b_hh only
                    if (g < 2) v += b_ih[r];     // r/z: both biases fused
                }
                vals[i] = f2bf(v);
            }
        } else {
            #pragma unroll
            for (int i = 0; i < 8; ++i) vals[i] = 0;
        }
        #pragma unroll
        for (int i = 0; i < 8; ++i) wlds[e * 8 + i] = vals[i];
    }
    // head weights -> LDS (fp32), zero-padded to 152
    for (int k = tid; k < 152; k += BDIM) {
        float v = 0.f;
        if (k < 100)      v = actor_w[k];
        else if (k < 150) v = critic_w[k - 100];
        awc[k] = v;
    }
    // n-gate input weights by output column (zero-padded)
    if (tid < 64) {
        int j = tid;
        float w0 = 0.f, w1 = 0.f, bb = 0.f;
        if (j < 50) {
            w0 = w_ih[(100 + j) * 2 + 0];
            w1 = w_ih[(100 + j) * 2 + 1];
            bb = b_ih[100 + j];
        }
        win0l[j] = w0; win1l[j] = w1; binl[j] = bb;
    }
    const float ab0 = actor_b[0], ab1 = actor_b[1], cb = critic_b[0];

    const float2* h2 = (const float2*)h;
    const float2* s2 = (const float2*)s;
    unsigned* xlds32 = (unsigned*)xlds;
    float2* out2 = (float2*)out;
    const long long outc_off   = (long long)Btot * 50;         // c, float idx
    const long long outpi2_off = ((long long)Btot * 51) >> 1;  // pi, float2 idx

    // ---- prefetch regs: 1664 float2 per tile (h:1600 + s:64) ----
    float2 pf[7];
    int bt = blockIdx.x;
    {
        int rb = bt * 64;
        #pragma unroll
        for (int j = 0; j < 7; ++j) {
            int d = tid + j * 256;
            if (d < 1600)       pf[j] = h2[rb * 25 + d];
            else if (d < 1664)  pf[j] = s2[rb + (d - 1600)];
        }
    }

    while (bt < nTiles) {
        const int rowbase = bt * 64;
        __syncthreads();                // prev heads done reading xlds
        // ---- regs -> LDS (bf16 x-tile, fp32 s) ----
        #pragma unroll
        for (int j = 0; j < 7; ++j) {
            int d = tid + j * 256;
            if (d < 1600) {
                int r = d / 25, dk = d - r * 25;
                xlds32[r * 36 + dk] = packbf(pf[j].x, pf[j].y);
            } else if (d < 1664) {
                int r = d - 1600;
                sflds[r * 2 + 0] = pf[j].x;
                sflds[r * 2 + 1] = pf[j].y;
                xlds32[r * 36 + 25] = packbf(pf[j].x, pf[j].y);
            }
        }
        if (tid < 64) {
            xlds32[tid * 36 + 26] = 0x00003f80u;   // k=52: 1.0 bf16, k=53: 0
            #pragma unroll
            for (int q = 27; q < 32; ++q) xlds32[tid * 36 + q] = 0u;
        }
        __syncthreads();

        // ---- issue next tile's global loads (latency hidden by compute) ----
        const int nbt = bt + gridDim.x;
        {
            int pb = (nbt < nTiles) ? nbt : bt;
            int rb = pb * 64;
            #pragma unroll
            for (int j = 0; j < 7; ++j) {
                int d = tid + j * 256;
                if (d < 1600)       pf[j] = h2[rb * 25 + d];
                else if (d < 1664)  pf[j] = s2[rb + (d - 1600)];
            }
        }

        // ---- MFMA: 16 rows x (3 gates x 64 cols) per wave ----
        const unsigned short* arow = &xlds[(wave * 16 + c16) * 72 + quad * 8];
        bf16x8 a0 = *(const bf16x8*)(arow);        // k 0..31
        bf16x8 a1 = *(const bf16x8*)(arow + 32);   // k 32..63
        f32x4 acc[3][4];
        #pragma unroll
        for (int g = 0; g < 3; ++g) {
            #pragma unroll
            for (int t = 0; t < 4; ++t) {
                f32x4 a = {0.f, 0.f, 0.f, 0.f};
                const unsigned short* wb = &wlds[(((g * 4 + t) * 2) * 64 + lane) * 8];
                bf16x8 b0 = *(const bf16x8*)(wb);
                bf16x8 b1 = *(const bf16x8*)(wb + 64 * 8);
                a = __builtin_amdgcn_mfma_f32_16x16x32_bf16(a0, b0, a, 0, 0, 0);
                a = __builtin_amdgcn_mfma_f32_16x16x32_bf16(a1, b1, a, 0, 0, 0);
                acc[g][t] = a;
            }
        }

        // ---- gate math; h_new fp32 -> global, bf16 -> xlds (own wave's rows) ----
        #pragma unroll
        for (int reg = 0; reg < 4; ++reg) {
            int lr = wave * 16 + quad * 4 + reg;   // C/D: row = quad*4+reg
            float s0 = sflds[lr * 2 + 0];
            float s1 = sflds[lr * 2 + 1];
            #pragma unroll
            for (int t = 0; t < 4; ++t) {
                int j = t * 16 + c16;              // C/D: col = c16
                float pr = acc[0][t][reg];
                float pz = acc[1][t][reg];
                float hn = acc[2][t][reg];
                float inn = fmaf(s1, win1l[j], fmaf(s0, win0l[j], binl[j]));
                float rg = __builtin_amdgcn_rcpf(1.f + __expf(-pr));
                float zg = __builtin_amdgcn_rcpf(1.f + __expf(-pz));
                float x = inn + rg * hn;
                x = fminf(fmaxf(x, -20.f), 20.f);
                float e2 = __expf(2.f * x);
                float ng = (e2 - 1.f) * __builtin_amdgcn_rcpf(e2 + 1.f);
                if (j < 50) {
                    float hv = bf2f(xlds[lr * 72 + j]);
                    float hnew = (1.f - zg) * ng + zg * hv;
                    out[(long long)(rowbase + lr) * 50 + j] = hnew;
                    xlds[lr * 72 + j] = f2bf(hnew);
                }
            }
        }
        __syncthreads();

        // ---- heads: all 256 threads; 4 lanes/row split-K + shfl reduce ----
        {
            int row = wave * 16 + (lane >> 2);     // local row 0..63
            int sub = lane & 3;
            int kn = (sub == 3) ? 11 : 13;
            float a0p = 0.f, a1p = 0.f, ccp = 0.f;
            #pragma unroll
            for (int i = 0; i < 13; ++i) {
                int k = sub * 13 + i;
                float hv = (i < kn) ? bf2f(xlds[row * 72 + k]) : 0.f;
                a0p = fmaf(hv, awc[k],       a0p);
                a1p = fmaf(hv, awc[50 + k],  a1p);
                ccp = fmaf(hv, awc[100 + k], ccp);
            }
            a0p += __shfl_xor(a0p, 1); a0p += __shfl_xor(a0p, 2);
            a1p += __shfl_xor(a1p, 1); a1p += __shfl_xor(a1p, 2);
            ccp += __shfl_xor(ccp, 1); ccp += __shfl_xor(ccp, 2);
            if (sub == 0) {
                int gr = rowbase + row;
                float A0 = a0p + ab0, A1 = a1p + ab1;
                out[outc_off + gr] = ccp + cb;
                float m = fmaxf(A0, A1);
                float e0 = __expf(A0 - m), e1 = __expf(A1 - m);
                float inv = 1.f / (e0 + e1);
                float2 pv; pv.x = e0 * inv; pv.y = e1 * inv;
                out2[outpi2_off + gr] = pv;
            }
        }
        bt = nbt;
    }
}

extern "C" void kernel_launch(void* const* d_in, const int* in_sizes, int n_in,
                              void* d_out, int out_size, void* d_ws, size_t ws_size,
                              hipStream_t stream) {
    const float* s        = (const float*)d_in[0];
    const float* h        = (const float*)d_in[1];
    const float* w_ih     = (const float*)d_in[2];
    const float* w_hh     = (const float*)d_in[3];
    const float* b_ih     = (const float*)d_in[4];
    const float* b_hh     = (const float*)d_in[5];
    const float* actor_w  = (const float*)d_in[6];
    const float* actor_b  = (const float*)d_in[7];
    const float* critic_w = (const float*)d_in[8];
    const float* critic_b = (const float*)d_in[9];
    float* out = (float*)d_out;

    int Btot = in_sizes[1] / 50;          // 262144
    int nTiles = Btot / 64;               // 4096 (exact)
    int grid = nTiles < 1024 ? nTiles : 1024;

    gru_fused<<<grid, BDIM, 0, stream>>>(s, h, w_ih, w_hh, b_ih, b_hh,
                                         actor_w, actor_b, critic_w, critic_b,
                                         out, Btot, nTiles);
}

// Round 7
// 142.525 us; speedup vs baseline: 1.2203x; 1.0060x over previous
//
#include <hip/hip_runtime.h>
#include <hip/hip_bf16.h>

// GRUCell (B=262144, IN=2, H=50) + critic + actor-softmax.
// Inputs fp32, outputs fp32: d_out = h_new[B,50] | c[B,1] | pi[B,2].
// Extended-K MFMA: x[64]=[h(50),s(2),1,0...], W[64]=[w_hh,w_ih,bias,0...].
// R7 = R6 (barrier-free wave-private bands) + ALIAS-SAFE LDS access:
// writes via may_alias u32, fragment reads via __builtin_memcpy, and a
// compiler memory fence between staging and reads. R6 failed because
// TBAA saw the type-punned LDS reads as independent of the staging
// writes once __syncthreads() was gone, and hoisted them (stale zeros).

#define BDIM 256

typedef __bf16 bf16x8 __attribute__((ext_vector_type(8)));
typedef float f32x4 __attribute__((ext_vector_type(4)));
typedef unsigned __attribute__((may_alias)) u32a;
typedef unsigned short __attribute__((may_alias)) u16a;

__device__ __forceinline__ float bf2f(unsigned short u) {
    union { unsigned u; float f; } x; x.u = ((unsigned)u) << 16; return x.f;
}
__device__ __forceinline__ unsigned short f2bf(float f) {   // init path only
    union { float f; unsigned u; } x; x.f = f;
    unsigned r = x.u + 0x7fffu + ((x.u >> 16) & 1u);
    return (unsigned short)(r >> 16);
}
__device__ __forceinline__ unsigned packbf(float a, float b) {  // v_cvt_pk_bf16_f32
    union { __hip_bfloat162 h; unsigned u; } c;
    c.h = __float22bfloat162_rn(make_float2(a, b));
    return c.u;
}
__device__ __forceinline__ bf16x8 ldsfrag(const unsigned short* p) {
    bf16x8 v; __builtin_memcpy(&v, p, 16); return v;   // alias-safe b128 read
}

__global__ __launch_bounds__(BDIM, 4) void gru_fused(
    const float* __restrict__ s,
    const float* __restrict__ h,
    const float* __restrict__ w_ih,
    const float* __restrict__ w_hh,
    const float* __restrict__ b_ih,
    const float* __restrict__ b_hh,
    const float* __restrict__ actor_w,
    const float* __restrict__ actor_b,
    const float* __restrict__ critic_w,
    const float* __restrict__ critic_b,
    float* __restrict__ out,
    int Btot, int nTiles)
{
    // bf16 x-tile: 64 rows x 72 shorts (144B stride); shorts 0..49 h, 50..51 s,
    // 52 = 1.0, 53..63 = 0 (constants written once at init), 64..71 pad.
    __shared__ __align__(16) unsigned short xlds[64 * 72];
    // weight B-fragments: [g(3)][t(4)][ks(2)][lane(64)][8 bf16]
    __shared__ __align__(16) unsigned short wlds[1536 * 8];

    const int tid  = threadIdx.x;
    const int wave = tid >> 6;
    const int lane = tid & 63;
    const int c16  = lane & 15;
    const int quad = lane >> 4;
    const int R    = wave * 16;          // this wave's private 16-row band

    u32a* xlds32 = (u32a*)xlds;

    // ---- init: constant zone of xlds (one pass, race-free) ----
    for (int i = tid; i < 2304; i += BDIM)
        xlds32[i] = ((i % 36) == 26) ? 0x00003f80u : 0u;   // k=52 -> 1.0 bf16

    // ---- init: swizzled bf16 weight fragments into wlds ----
    for (int e = tid; e < 1536; e += BDIM) {
        int ln = e & 63;
        int ks = (e >> 6) & 1;
        int t  = (e >> 7) & 3;
        int g  = e >> 9;
        int n  = t * 16 + (ln & 15);
        int kbase = ks * 32 + (ln >> 4) * 8;
        unsigned short vals[8];
        if (n < 50) {
            int r = g * 50 + n;
            #pragma unroll
            for (int i = 0; i < 8; ++i) {
                int k = kbase + i;
                float v = 0.f;
                if (k < 50)       v = w_hh[r * 50 + k];
                else if (k == 50) v = (g < 2) ? w_ih[r * 2 + 0] : 0.f;
                else if (k == 51) v = (g < 2) ? w_ih[r * 2 + 1] : 0.f;
                else if (k == 52) {
                    v = b_hh[r];                 // n-gate: b_hh only
                    if (g < 2) v += b_ih[r];     // r/z: both biases fused
                }
                vals[i] = f2bf(v);
            }
        } else {
            #pragma unroll
            for (int i = 0; i < 8; ++i) vals[i] = 0;
        }
        #pragma unroll
        for (int i = 0; i < 8; ++i) wlds[e * 8 + i] = vals[i];
    }

    // ---- hoisted per-lane constants (loop-invariant global reads) ----
    float wi0[4], wi1[4], bi[4], aw0[4], aw1[4], awc[4];
    #pragma unroll
    for (int t = 0; t < 4; ++t) {
        int j = t * 16 + c16;
        bool ok = (j < 50);
        wi0[t] = ok ? w_ih[(100 + j) * 2 + 0] : 0.f;
        wi1[t] = ok ? w_ih[(100 + j) * 2 + 1] : 0.f;
        bi[t]  = ok ? b_ih[100 + j]           : 0.f;
        aw0[t] = ok ? actor_w[j]              : 0.f;
        aw1[t] = ok ? actor_w[50 + j]         : 0.f;
        awc[t] = ok ? critic_w[j]             : 0.f;
    }
    const float ab0 = actor_b[0], ab1 = actor_b[1], cb = critic_b[0];

    __syncthreads();   // the ONLY barrier: wlds + xlds const zone visible

    const float2* h2 = (const float2*)h;
    const float2* s2 = (const float2*)s;
    const long long outc = (long long)Btot * 50;
    float2* opi = (float2*)(out + (long long)Btot * 51);

    // ---- prefetch first tile (this wave's 16 rows: 400 h-float2 + 16 s) ----
    float2 pf[7];
    int bt = blockIdx.x;
    {
        long long hb = (long long)(bt * 64 + R) * 25;
        #pragma unroll
        for (int j = 0; j < 6; ++j) pf[j] = h2[hb + lane + j * 64];
        if (lane < 16)      pf[6] = h2[hb + 384 + lane];
        else if (lane < 32) pf[6] = s2[bt * 64 + R + lane - 16];
    }

    while (bt < nTiles) {
        const int rowbase = bt * 64;

        // ---- stage own band: regs -> LDS (alias-safe u32a writes) ----
        #pragma unroll
        for (int j = 0; j < 6; ++j) {
            int d = lane + j * 64;
            int r = d / 25, dk = d - r * 25;
            xlds32[(R + r) * 36 + dk] = packbf(pf[j].x, pf[j].y);
        }
        if (lane < 16)
            xlds32[(R + 15) * 36 + 9 + lane] = packbf(pf[6].x, pf[6].y);
        else if (lane < 32)
            xlds32[(R + lane - 16) * 36 + 25] = packbf(pf[6].x, pf[6].y);

        // compiler fence: staging writes ordered before all following reads
        asm volatile("" ::: "memory");

        // ---- issue next tile's loads (latency hidden by compute) ----
        const int nbt = bt + gridDim.x;
        {
            int pb = (nbt < nTiles) ? nbt : bt;
            long long hb = (long long)(pb * 64 + R) * 25;
            #pragma unroll
            for (int j = 0; j < 6; ++j) pf[j] = h2[hb + lane + j * 64];
            if (lane < 16)      pf[6] = h2[hb + 384 + lane];
            else if (lane < 32) pf[6] = s2[pb * 64 + R + lane - 16];
        }

        // ---- s rows for gate math (L2-hot, 16-lane broadcast) ----
        float2 srow[4];
        #pragma unroll
        for (int reg = 0; reg < 4; ++reg)
            srow[reg] = s2[rowbase + R + quad * 4 + reg];

        // ---- A fragments (own band, alias-safe reads) ----
        const unsigned short* arow = &xlds[(R + c16) * 72 + quad * 8];
        bf16x8 a0 = ldsfrag(arow);        // k 0..31
        bf16x8 a1 = ldsfrag(arow + 32);   // k 32..63

        // ---- per-t: 6 MFMAs then gate math ----
        float hn_r[4][4];
        #pragma unroll
        for (int t = 0; t < 4; ++t) {
            f32x4 ar = {0.f,0.f,0.f,0.f}, az = ar, an = ar;
            const int tb = (t * 128 + lane) * 8;   // shorts; ks +512, g +4096
            bf16x8 br0 = ldsfrag(&wlds[tb]);
            bf16x8 br1 = ldsfrag(&wlds[tb + 512]);
            bf16x8 bz0 = ldsfrag(&wlds[tb + 4096]);
            bf16x8 bz1 = ldsfrag(&wlds[tb + 4608]);
            bf16x8 bn0 = ldsfrag(&wlds[tb + 8192]);
            bf16x8 bn1 = ldsfrag(&wlds[tb + 8704]);
            ar = __builtin_amdgcn_mfma_f32_16x16x32_bf16(a0, br0, ar, 0, 0, 0);
            ar = __builtin_amdgcn_mfma_f32_16x16x32_bf16(a1, br1, ar, 0, 0, 0);
            az = __builtin_amdgcn_mfma_f32_16x16x32_bf16(a0, bz0, az, 0, 0, 0);
            az = __builtin_amdgcn_mfma_f32_16x16x32_bf16(a1, bz1, az, 0, 0, 0);
            an = __builtin_amdgcn_mfma_f32_16x16x32_bf16(a0, bn0, an, 0, 0, 0);
            an = __builtin_amdgcn_mfma_f32_16x16x32_bf16(a1, bn1, an, 0, 0, 0);

            int j = t * 16 + c16;
            #pragma unroll
            for (int reg = 0; reg < 4; ++reg) {
                int lr = R + quad * 4 + reg;       // C/D: row = quad*4+reg
                float inn = fmaf(srow[reg].y, wi1[t],
                            fmaf(srow[reg].x, wi0[t], bi[t]));
                float rg = __builtin_amdgcn_rcpf(1.f + __expf(-ar[reg]));
                float zg = __builtin_amdgcn_rcpf(1.f + __expf(-az[reg]));
                float x = inn + rg * an[reg];
                x = fminf(fmaxf(x, -20.f), 20.f);
                float e2 = __expf(2.f * x);
                float ng = (e2 - 1.f) * __builtin_amdgcn_rcpf(e2 + 1.f);
                float hv = bf2f(((const u16a*)xlds)[lr * 72 + j]);
                float hnew = (1.f - zg) * ng + zg * hv;
                bool ok = (j < 50);
                hn_r[reg][t] = ok ? hnew : 0.f;
                if (ok) out[(long long)(rowbase + lr) * 50 + j] = hnew;
            }
        }

        // ---- heads from registers: 16-lane shfl_xor butterfly per row ----
        float sum0[4], sum1[4], sumc[4];
        #pragma unroll
        for (int reg = 0; reg < 4; ++reg) {
            float p0 = 0.f, p1 = 0.f, pc = 0.f;
            #pragma unroll
            for (int t = 0; t < 4; ++t) {
                p0 = fmaf(hn_r[reg][t], aw0[t], p0);
                p1 = fmaf(hn_r[reg][t], aw1[t], p1);
                pc = fmaf(hn_r[reg][t], awc[t], pc);
            }
            #pragma unroll
            for (int m = 1; m < 16; m <<= 1) {
                p0 += __shfl_xor(p0, m);
                p1 += __shfl_xor(p1, m);
                pc += __shfl_xor(pc, m);
            }
            sum0[reg] = p0; sum1[reg] = p1; sumc[reg] = pc;
        }
        if (c16 < 4) {   // lane c16==reg writes row quad*4+c16
            float A0 = (c16 == 0) ? sum0[0] : (c16 == 1) ? sum0[1]
                     : (c16 == 2) ? sum0[2] : sum0[3];
            float A1 = (c16 == 0) ? sum1[0] : (c16 == 1) ? sum1[1]
                     : (c16 == 2) ? sum1[2] : sum1[3];
            float C  = (c16 == 0) ? sumc[0] : (c16 == 1) ? sumc[1]
                     : (c16 == 2) ? sumc[2] : sumc[3];
            int gr = rowbase + R + quad * 4 + c16;
            out[outc + gr] = C + cb;
            A0 += ab0; A1 += ab1;
            float m = fmaxf(A0, A1);
            float e0 = __expf(A0 - m), e1 = __expf(A1 - m);
            float inv = 1.f / (e0 + e1);
            float2 pv; pv.x = e0 * inv; pv.y = e1 * inv;
            opi[gr] = pv;
        }
        bt = nbt;
    }
}

extern "C" void kernel_launch(void* const* d_in, const int* in_sizes, int n_in,
                              void* d_out, int out_size, void* d_ws, size_t ws_size,
                              hipStream_t stream) {
    const float* s        = (const float*)d_in[0];
    const float* h        = (const float*)d_in[1];
    const float* w_ih     = (const float*)d_in[2];
    const float* w_hh     = (const float*)d_in[3];
    const float* b_ih     = (const float*)d_in[4];
    const float* b_hh     = (const float*)d_in[5];
    const float* actor_w  = (const float*)d_in[6];
    const float* actor_b  = (const float*)d_in[7];
    const float* critic_w = (const float*)d_in[8];
    const float* critic_b = (const float*)d_in[9];
    float* out = (float*)d_out;

    int Btot = in_sizes[1] / 50;          // 262144
    int nTiles = Btot / 64;               // 4096 (exact)
    int grid = nTiles < 1024 ? nTiles : 1024;

    gru_fused<<<grid, BDIM, 0, stream>>>(s, h, w_ih, w_hh, b_ih, b_hh,
                                         actor_w, actor_b, critic_w, critic_b,
                                         out, Btot, nTiles);
}